// Round 1
// baseline (2236.641 us; speedup 1.0000x reference)
//
#include <hip/hip_runtime.h>

#define S 16
#define B 8
#define H 16
#define DH 64
#define D 1024
#define HD 1024          // H*DH
#define LC 8192
#define LMAX (LC + S)    // 8208

// ---------------- cache copy: cache_k/v -> new_k/v[0:LC] ----------------
__global__ __launch_bounds__(256) void copy_cache(const float4* __restrict__ ck,
                                                  const float4* __restrict__ cv,
                                                  float4* __restrict__ nk,
                                                  float4* __restrict__ nv, int n4)
{
    int stride = gridDim.x * blockDim.x;
    for (int i = blockIdx.x * blockDim.x + threadIdx.x; i < n4; i += stride) {
        nk[i] = ck[i];
        nv[i] = cv[i];
    }
}

// ---------------- QKV projection ----------------
// grid = 128 rows * 3 mats * 4 chunks; block = 256
__global__ __launch_bounds__(256) void proj_qkv(const float* __restrict__ x,
        const float* __restrict__ Wq, const float* __restrict__ Wk,
        const float* __restrict__ Wv,
        float* __restrict__ q_ws, float* __restrict__ newk, float* __restrict__ newv)
{
    __shared__ float xs[D];
    int bx = blockIdx.x;
    int row = bx / 12;          // s*B + b
    int rem = bx % 12;
    int mat = rem >> 2;
    int chunk = rem & 3;
    int tid = threadIdx.x;

    ((float4*)xs)[tid] = ((const float4*)(x + (size_t)row * D))[tid];
    __syncthreads();

    const float* W = (mat == 0) ? Wq : ((mat == 1) ? Wk : Wv);
    int o = chunk * 256 + tid;
    float a0 = 0.f, a1 = 0.f, a2 = 0.f, a3 = 0.f;
    for (int d = 0; d < D; d += 4) {
        a0 += xs[d + 0] * W[(size_t)(d + 0) * HD + o];
        a1 += xs[d + 1] * W[(size_t)(d + 1) * HD + o];
        a2 += xs[d + 2] * W[(size_t)(d + 2) * HD + o];
        a3 += xs[d + 3] * W[(size_t)(d + 3) * HD + o];
    }
    float acc = (a0 + a1) + (a2 + a3);

    int s = row / B, b = row % B;
    if (mat == 0) {
        q_ws[(size_t)row * HD + o] = acc;
    } else {
        float* dst = (mat == 1) ? newk : newv;
        dst[(size_t)((LC + s) * B + b) * HD + o] = acc;   // append at t = LC+s
    }
}

// ---------------- attention: one block per (b,h,s) ----------------
__global__ __launch_bounds__(256) void attn(const float* __restrict__ q_ws,
        const float* __restrict__ newk, const float* __restrict__ newv,
        float* __restrict__ ctx)
{
    __shared__ float sc[LMAX];
    __shared__ float qs[DH];
    __shared__ float red[256];
    __shared__ float pv[4][DH];

    int bx = blockIdx.x;
    int s = bx % S;             // s fastest: 16 consecutive blocks share (b,h) K/V slice
    int bh = bx / S;
    int h = bh % H;
    int b = bh / H;
    int tid = threadIdx.x;
    int Ls = LC + s + 1;

    if (tid < DH) qs[tid] = q_ws[(size_t)(s * B + b) * HD + h * DH + tid];
    __syncthreads();

    // scores: lane-per-t, per-lane contiguous 256B K row
    float lmax = -1e30f;
    for (int t = tid; t < Ls; t += 256) {
        const float4* kr = (const float4*)(newk + (size_t)(t * B + b) * HD + h * DH);
        const float4* q4 = (const float4*)qs;
        float acc = 0.f;
        #pragma unroll
        for (int i = 0; i < DH / 4; ++i) {
            float4 k = kr[i], q = q4[i];
            acc += k.x * q.x + k.y * q.y + k.z * q.z + k.w * q.w;
        }
        acc *= 0.125f;           // 1/sqrt(64)
        sc[t] = acc;
        lmax = fmaxf(lmax, acc);
    }
    red[tid] = lmax;
    __syncthreads();
    for (int w = 128; w > 0; w >>= 1) {
        if (tid < w) red[tid] = fmaxf(red[tid], red[tid + w]);
        __syncthreads();
    }
    float m = red[0];
    __syncthreads();

    float lsum = 0.f;
    for (int t = tid; t < Ls; t += 256) {
        float p = __expf(sc[t] - m);
        sc[t] = p;
        lsum += p;
    }
    red[tid] = lsum;
    __syncthreads();
    for (int w = 128; w > 0; w >>= 1) {
        if (tid < w) red[tid] += red[tid + w];
        __syncthreads();
    }
    float denom = red[0];
    __syncthreads();

    // PV: lanes d-parallel (coalesced 256B V rows), 4 t-groups
    int d = tid & 63, tg = tid >> 6;
    float acc = 0.f;
    for (int t = tg; t < Ls; t += 4) {
        acc += sc[t] * newv[(size_t)(t * B + b) * HD + h * DH + d];
    }
    pv[tg][d] = acc;
    __syncthreads();
    if (tid < DH) {
        float r = (pv[0][tid] + pv[1][tid] + pv[2][tid] + pv[3][tid]) / denom;
        ctx[(size_t)(s * B + b) * HD + h * DH + tid] = r;
    }
}

// ---------------- output projection ----------------
// grid = 128 rows * 4 chunks; block = 256
__global__ __launch_bounds__(256) void proj_o(const float* __restrict__ ctx,
                                              const float* __restrict__ Wo,
                                              float* __restrict__ res)
{
    __shared__ float cs[HD];
    int bx = blockIdx.x;
    int row = bx >> 2;
    int chunk = bx & 3;
    int tid = threadIdx.x;

    ((float4*)cs)[tid] = ((const float4*)(ctx + (size_t)row * HD))[tid];
    __syncthreads();

    int o = chunk * 256 + tid;
    float a0 = 0.f, a1 = 0.f, a2 = 0.f, a3 = 0.f;
    for (int d = 0; d < HD; d += 4) {
        a0 += cs[d + 0] * Wo[(size_t)(d + 0) * D + o];
        a1 += cs[d + 1] * Wo[(size_t)(d + 1) * D + o];
        a2 += cs[d + 2] * Wo[(size_t)(d + 2) * D + o];
        a3 += cs[d + 3] * Wo[(size_t)(d + 3) * D + o];
    }
    res[(size_t)row * D + o] = (a0 + a1) + (a2 + a3);
}

extern "C" void kernel_launch(void* const* d_in, const int* in_sizes, int n_in,
                              void* d_out, int out_size, void* d_ws, size_t ws_size,
                              hipStream_t stream)
{
    const float* x  = (const float*)d_in[0];
    const float* ck = (const float*)d_in[1];
    const float* cv = (const float*)d_in[2];
    const float* Wq = (const float*)d_in[3];
    const float* Wk = (const float*)d_in[4];
    const float* Wv = (const float*)d_in[5];
    const float* Wo = (const float*)d_in[6];

    float* out  = (float*)d_out;
    float* res  = out;                                   // (S,B,D)
    float* newk = out + (size_t)S * B * D;               // (L,B,H,DH)
    float* newv = newk + (size_t)LMAX * B * H * DH;

    float* q_ws = (float*)d_ws;                          // (S,B,HD)
    float* ctx  = q_ws + (size_t)S * B * HD;             // (S,B,HD)

    int n4 = LC * B * H * DH / 4;                        // 16,777,216 float4 per array
    hipLaunchKernelGGL(copy_cache, dim3(2048), dim3(256), 0, stream,
                       (const float4*)ck, (const float4*)cv,
                       (float4*)newk, (float4*)newv, n4);
    hipLaunchKernelGGL(proj_qkv, dim3(128 * 12), dim3(256), 0, stream,
                       x, Wq, Wk, Wv, q_ws, newk, newv);
    hipLaunchKernelGGL(attn, dim3(B * H * S), dim3(256), 0, stream,
                       q_ws, newk, newv, ctx);
    hipLaunchKernelGGL(proj_o, dim3(128 * 4), dim3(256), 0, stream,
                       ctx, Wo, res);
}

// Round 2
// 430.076 us; speedup vs baseline: 5.2006x; 5.2006x over previous
//
#include <hip/hip_runtime.h>

#define S 16
#define B 8
#define H 16
#define DH 64
#define D 1024
#define HD 1024          // H*DH
#define LC 8192
#define LMAX (LC + S)    // 8208
#define NCH 16           // L-chunks per (b,h)
#define CHT 512          // t rows per chunk
#define ST 64            // subtile rows staged in LDS
#define KPAD 68          // padded row length (floats), 16B-aligned, bank-friendly

// ---------------- QKV projection (writes q to ws, k/v tails into d_out) ----
__global__ __launch_bounds__(256) void proj_qkv(const float* __restrict__ x,
        const float* __restrict__ Wq, const float* __restrict__ Wk,
        const float* __restrict__ Wv,
        float* __restrict__ q_ws, float* __restrict__ newk, float* __restrict__ newv)
{
    __shared__ float xs[D];
    int bx = blockIdx.x;
    int row = bx / 12;          // s*B + b
    int rem = bx % 12;
    int mat = rem >> 2;
    int chunk = rem & 3;
    int tid = threadIdx.x;

    ((float4*)xs)[tid] = ((const float4*)(x + (size_t)row * D))[tid];
    __syncthreads();

    const float* W = (mat == 0) ? Wq : ((mat == 1) ? Wk : Wv);
    int o = chunk * 256 + tid;
    float a0 = 0.f, a1 = 0.f, a2 = 0.f, a3 = 0.f;
    for (int d = 0; d < D; d += 4) {
        a0 += xs[d + 0] * W[(size_t)(d + 0) * HD + o];
        a1 += xs[d + 1] * W[(size_t)(d + 1) * HD + o];
        a2 += xs[d + 2] * W[(size_t)(d + 2) * HD + o];
        a3 += xs[d + 3] * W[(size_t)(d + 3) * HD + o];
    }
    float acc = (a0 + a1) + (a2 + a3);

    int s = row / B, b = row % B;
    if (mat == 0) {
        q_ws[(size_t)row * HD + o] = acc;
    } else {
        float* dst = (mat == 1) ? newk : newv;
        dst[(size_t)((LC + s) * B + b) * HD + o] = acc;   // append at t = LC+s
    }
}

// ---------------- fused cache-copy + flash attention over one L-chunk ------
// grid = B*H*NCH blocks (bh*16 + chunk), block = 256 (4 waves)
// wave w handles s in [4w, 4w+4); lane = t (scores) or d (PV)
__global__ __launch_bounds__(256) void attn_fused(const float* __restrict__ q_ws,
        const float* __restrict__ cache_k, const float* __restrict__ cache_v,
        float* __restrict__ newk, float* __restrict__ newv,
        float* __restrict__ m_part, float* __restrict__ l_part,
        float* __restrict__ pv_part)
{
    __shared__ float Ks[ST][KPAD];
    __shared__ float Vs[ST][KPAD];
    __shared__ float qs[S][KPAD];
    __shared__ float sc[S][ST];

    int chunk = blockIdx.x & 15;
    int bh    = blockIdx.x >> 4;
    int h = bh & 15;
    int b = bh >> 4;
    int tid  = threadIdx.x;
    int lane = tid & 63;
    int sg   = tid >> 6;        // wave id == s-group

    // load q tile (16 rows x 64) into LDS
    {
        int r = tid >> 4, c = tid & 15;
        *(float4*)&qs[r][c * 4] =
            *(const float4*)(q_ws + ((size_t)(r * B + b)) * HD + h * DH + c * 4);
    }

    float m_prev[4], l_acc[4], pv_acc[4];
    #pragma unroll
    for (int j = 0; j < 4; ++j) { m_prev[j] = -1e30f; l_acc[j] = 0.f; pv_acc[j] = 0.f; }

    int nsub = (chunk == NCH - 1) ? 9 : 8;   // last chunk also does the 16-row tail

    for (int it = 0; it < nsub; ++it) {
        bool tail  = (it == 8);
        int  t0    = chunk * CHT + it * ST;   // global t of subtile row 0
        int  nrows = tail ? S : ST;

        __syncthreads();   // protect LDS from previous iteration's readers
        // ---- stage K/V subtile into LDS; write cache rows out to newk/newv
        {
            int r = tid >> 4, c = tid & 15;
            #pragma unroll
            for (int g = 0; g < 4; ++g, r += 16) {
                if (r < nrows) {
                    size_t off = ((size_t)(t0 + r) * B + b) * HD + h * DH + c * 4;
                    if (!tail) {
                        float4 k4 = *(const float4*)(cache_k + off);
                        float4 v4 = *(const float4*)(cache_v + off);
                        *(float4*)&Ks[r][c * 4] = k4;
                        *(float4*)&Vs[r][c * 4] = v4;
                        *(float4*)(newk + off) = k4;    // the cache copy
                        *(float4*)(newv + off) = v4;
                    } else {                            // tail rows already in newk/newv
                        *(float4*)&Ks[r][c * 4] = *(const float4*)(newk + off);
                        *(float4*)&Vs[r][c * 4] = *(const float4*)(newv + off);
                    }
                }
            }
        }
        __syncthreads();

        // ---- scores: lane = t, 4 s per thread, K row vectorized from LDS
        float a0 = 0.f, a1 = 0.f, a2 = 0.f, a3 = 0.f;
        #pragma unroll
        for (int i = 0; i < 16; ++i) {
            float4 k4 = *(float4*)&Ks[lane][i * 4];
            float4 q0 = *(float4*)&qs[sg * 4 + 0][i * 4];
            float4 q1 = *(float4*)&qs[sg * 4 + 1][i * 4];
            float4 q2 = *(float4*)&qs[sg * 4 + 2][i * 4];
            float4 q3 = *(float4*)&qs[sg * 4 + 3][i * 4];
            a0 += k4.x * q0.x + k4.y * q0.y + k4.z * q0.z + k4.w * q0.w;
            a1 += k4.x * q1.x + k4.y * q1.y + k4.z * q1.z + k4.w * q1.w;
            a2 += k4.x * q2.x + k4.y * q2.y + k4.z * q2.z + k4.w * q2.w;
            a3 += k4.x * q3.x + k4.y * q3.y + k4.z * q3.z + k4.w * q3.w;
        }
        float a[4] = { a0 * 0.125f, a1 * 0.125f, a2 * 0.125f, a3 * 0.125f };

        // mask: valid iff lane < nrows and t_global <= LC + s (only tail can fail)
        int tg = t0 + lane;
        #pragma unroll
        for (int j = 0; j < 4; ++j) {
            int s = sg * 4 + j;
            if (lane >= nrows || tg > LC + s) a[j] = -1e30f;
        }

        // wave max-reduce per s, online rescale factors, exp -> sc
        float scale_f[4];
        #pragma unroll
        for (int j = 0; j < 4; ++j) {
            float v = a[j];
            #pragma unroll
            for (int msk = 32; msk; msk >>= 1) v = fmaxf(v, __shfl_xor(v, msk));
            float mn = fmaxf(m_prev[j], v);
            scale_f[j] = __expf(m_prev[j] - mn);
            m_prev[j] = mn;
            sc[sg * 4 + j][lane] = __expf(a[j] - mn);  // exp(-huge) == 0 for masked
        }
        __syncthreads();

        // ---- PV: lane = d, accumulate 4 s
        #pragma unroll
        for (int j = 0; j < 4; ++j) { l_acc[j] *= scale_f[j]; pv_acc[j] *= scale_f[j]; }
        for (int tt = 0; tt < 16; ++tt) {
            float v0 = Vs[tt * 4 + 0][lane];
            float v1 = Vs[tt * 4 + 1][lane];
            float v2 = Vs[tt * 4 + 2][lane];
            float v3 = Vs[tt * 4 + 3][lane];
            #pragma unroll
            for (int j = 0; j < 4; ++j) {
                float4 p = *(float4*)&sc[sg * 4 + j][tt * 4];
                pv_acc[j] += p.x * v0 + p.y * v1 + p.z * v2 + p.w * v3;
                l_acc[j]  += p.x + p.y + p.z + p.w;
            }
        }
    }

    // ---- emit partials: pi = blockIdx.x
    int pi = blockIdx.x;
    #pragma unroll
    for (int j = 0; j < 4; ++j) {
        int s = sg * 4 + j;
        pv_part[((size_t)pi * S + s) * DH + lane] = pv_acc[j];
        if (lane == 0) {
            m_part[pi * S + s] = m_prev[j];
            l_part[pi * S + s] = l_acc[j];
        }
    }
}

// ---------------- combine partials over chunks -> ctx ----------------------
// grid = B*H*S (bh*16 + s), block = 64 (lane = d)
__global__ __launch_bounds__(64) void combine(const float* __restrict__ m_part,
        const float* __restrict__ l_part, const float* __restrict__ pv_part,
        float* __restrict__ ctx)
{
    int s  = blockIdx.x & 15;
    int bh = blockIdx.x >> 4;
    int h = bh & 15;
    int b = bh >> 4;
    int d = threadIdx.x;

    float M = -1e30f;
    #pragma unroll
    for (int c = 0; c < NCH; ++c) M = fmaxf(M, m_part[(bh * NCH + c) * S + s]);
    float L = 0.f, acc = 0.f;
    #pragma unroll
    for (int c = 0; c < NCH; ++c) {
        int pi = bh * NCH + c;
        float w = __expf(m_part[pi * S + s] - M);
        L   += l_part[pi * S + s] * w;
        acc += w * pv_part[((size_t)pi * S + s) * DH + d];
    }
    ctx[((size_t)(s * B + b)) * HD + h * DH + d] = acc / L;
}

// ---------------- output projection ----------------
__global__ __launch_bounds__(256) void proj_o(const float* __restrict__ ctx,
                                              const float* __restrict__ Wo,
                                              float* __restrict__ res)
{
    __shared__ float cs[HD];
    int bx = blockIdx.x;
    int row = bx >> 2;
    int chunk = bx & 3;
    int tid = threadIdx.x;

    ((float4*)cs)[tid] = ((const float4*)(ctx + (size_t)row * HD))[tid];
    __syncthreads();

    int o = chunk * 256 + tid;
    float a0 = 0.f, a1 = 0.f, a2 = 0.f, a3 = 0.f;
    for (int d = 0; d < HD; d += 4) {
        a0 += cs[d + 0] * Wo[(size_t)(d + 0) * D + o];
        a1 += cs[d + 1] * Wo[(size_t)(d + 1) * D + o];
        a2 += cs[d + 2] * Wo[(size_t)(d + 2) * D + o];
        a3 += cs[d + 3] * Wo[(size_t)(d + 3) * D + o];
    }
    res[(size_t)row * D + o] = (a0 + a1) + (a2 + a3);
}

extern "C" void kernel_launch(void* const* d_in, const int* in_sizes, int n_in,
                              void* d_out, int out_size, void* d_ws, size_t ws_size,
                              hipStream_t stream)
{
    const float* x  = (const float*)d_in[0];
    const float* ck = (const float*)d_in[1];
    const float* cv = (const float*)d_in[2];
    const float* Wq = (const float*)d_in[3];
    const float* Wk = (const float*)d_in[4];
    const float* Wv = (const float*)d_in[5];
    const float* Wo = (const float*)d_in[6];

    float* out  = (float*)d_out;
    float* res  = out;                                   // (S,B,D)
    float* newk = out + (size_t)S * B * D;               // (L,B,H,DH)
    float* newv = newk + (size_t)LMAX * B * H * DH;

    float* q_ws    = (float*)d_ws;                            // 131072 f
    float* ctx     = q_ws + (size_t)S * B * HD;               // 131072 f
    float* m_part  = ctx + (size_t)S * B * HD;                // 128*16*16 f
    float* l_part  = m_part + (size_t)B * H * NCH * S;        // 128*16*16 f
    float* pv_part = l_part + (size_t)B * H * NCH * S;        // 128*16*16*64 f

    hipLaunchKernelGGL(proj_qkv, dim3(128 * 12), dim3(256), 0, stream,
                       x, Wq, Wk, Wv, q_ws, newk, newv);
    hipLaunchKernelGGL(attn_fused, dim3(B * H * NCH), dim3(256), 0, stream,
                       q_ws, ck, cv, newk, newv, m_part, l_part, pv_part);
    hipLaunchKernelGGL(combine, dim3(B * H * S), dim3(64), 0, stream,
                       m_part, l_part, pv_part, ctx);
    hipLaunchKernelGGL(proj_o, dim3(128 * 4), dim3(256), 0, stream,
                       ctx, Wo, res);
}